// Round 10
// baseline (645.376 us; speedup 1.0000x reference)
//
#include <hip/hip_runtime.h>
#include <hip/hip_bf16.h>

constexpr int U_N = 100000;
constexpr int I_N = 50000;
constexpr int KDIM = 64;
constexpr float EPSF = 1e-12f;

// bucketed CSR build params
constexpr int RPB = 256;        // rows per bucket (dst & 255 fits in low 8 w-mantissa bits)
constexpr int BSHIFT = 8;       // bucket = dst >> 8
constexpr int CH = 16384;       // edges per partition chunk (16/thread; runs ~28 edges -> line-owned)
constexpr int CAPB = 9216;      // fixed bucket capacity (mean 8192, +11 sigma; P(overflow)~1e-29)

typedef float f4 __attribute__((ext_vector_type(4)));
typedef unsigned short u16;

__device__ inline f4 ld4(const float* p) { return *(const f4*)p; }

// pack two f32 -> two bf16 (RNE) in one uint32
__device__ inline unsigned pack_bf16(float a, float b) {
    unsigned ua = __float_as_uint(a);
    unsigned ub = __float_as_uint(b);
    ua += 0x7fffu + ((ua >> 16) & 1u);
    ub += 0x7fffu + ((ub >> 16) & 1u);
    return (ua >> 16) | (ub & 0xffff0000u);
}

// unpack 8 bf16 (uint4) -> 8 f32
__device__ inline void bf8_to_f32(uint4 u, float* f) {
    unsigned w0 = u.x, w1 = u.y, w2 = u.z, w3 = u.w;
    f[0] = __uint_as_float(w0 << 16);  f[1] = __uint_as_float(w0 & 0xffff0000u);
    f[2] = __uint_as_float(w1 << 16);  f[3] = __uint_as_float(w1 & 0xffff0000u);
    f[4] = __uint_as_float(w2 << 16);  f[5] = __uint_as_float(w2 & 0xffff0000u);
    f[6] = __uint_as_float(w3 << 16);  f[7] = __uint_as_float(w3 & 0xffff0000u);
}

// ---------------- bucketed CSR build, fixed-capacity buckets ----------------
// Pass 1 (bpart2): one 16384-edge chunk per block, two passes over the chunk:
//   (A) histogram dst buckets (LDS); (B) per-bucket global reservation; then
//   re-read dst (L2-hot) + src/w (first read) and scatter directly into the
//   bucket-strided pairs region. Runs avg ~28 edges (224B) so most 64B lines
//   are single-writer -> merge in the writing XCD's L2.
// dlo (dst&255) is embedded in the low 8 mantissa bits of w -> no dlo array.
__global__ __launch_bounds__(1024) void bpart2_k(
        const int* __restrict__ srcU, const int* __restrict__ dstU,
        const float* __restrict__ wU, int* __restrict__ curU,
        int2* __restrict__ pairsU, int nchU, int EU,
        const int* __restrict__ srcI, const int* __restrict__ dstI,
        const float* __restrict__ wI, int* __restrict__ curI,
        int2* __restrict__ pairsI, int EI) {
    __shared__ int hist[1024];
    __shared__ int rb[1024];
    int t = threadIdx.x;
    int c = blockIdx.x;
    const int* src; const int* dst; const float* w; int* gcur; int2* pairs;
    int cb, E;
    if (c < nchU) { src = srcU; dst = dstU; w = wU; gcur = curU; pairs = pairsU;
                    cb = c * CH; E = EU; }
    else          { src = srcI; dst = dstI; w = wI; gcur = curI; pairs = pairsI;
                    cb = (c - nchU) * CH; E = EI; }
    int n = min(CH, E - cb);
    hist[t] = 0;
    __syncthreads();
    for (int j = t; j < n; j += 1024)
        atomicAdd(&hist[dst[cb + j] >> BSHIFT], 1);
    __syncthreads();
    int cnt_t = hist[t];
    if (cnt_t > 0) rb[t] = atomicAdd(&gcur[t], cnt_t);  // cnt>0 => t < NB (in-bounds)
    hist[t] = 0;   // becomes local placement cursor (own-slot RMW, no cross-thread hazard)
    __syncthreads();
    for (int j = t; j < n; j += 1024) {
        int i = cb + j;
        int d = dst[i];              // L2-hot re-read
        int b = d >> BSHIFT;
        int ew = (int)((__float_as_uint(w[i]) & 0xFFFFFF00u) | (unsigned)(d & (RPB - 1)));
        int local = atomicAdd(&hist[b], 1);
        int off = rb[b] + local;
        if (off < CAPB)   // defensive: provably in-bounds for any input
            pairs[(size_t)b * CAPB + off] = make_int2(src[i], ew);
    }
}

// Pass 2 (bfill2): one bucket per block, no LDS staging (the 72KB bucket region
// is L2-resident for the re-read). Per-row histogram + shfl-based scan, emit
// int2 row ranges, counting-sort scatter into a compact e2 region claimed via
// an atomic ticket (bucket placement order is schedule-dependent; row ranges
// carry absolute positions so compute is exact).
__global__ __launch_bounds__(1024) void bfill2_k(
        const int* __restrict__ curU, const int2* __restrict__ pairsU,
        int2* __restrict__ e2U, int2* __restrict__ rowsU, int NBu, int NRu,
        int* __restrict__ ecurU,
        const int* __restrict__ curI, const int2* __restrict__ pairsI,
        int2* __restrict__ e2I, int2* __restrict__ rowsI, int NRi,
        int* __restrict__ ecurI) {
    __shared__ int hist[RPB];
    __shared__ int pos[RPB + 1];
    __shared__ int wsums[4];
    __shared__ int sbase;
    int t = threadIdx.x;  // 1024
    int b = blockIdx.x;
    const int2* pairs; int2* e2; int2* rows; const int* cur; int* ecur; int bb, Nrows;
    if (b < NBu) { pairs = pairsU; e2 = e2U; rows = rowsU; cur = curU; ecur = ecurU;
                   bb = b; Nrows = NRu; }
    else         { pairs = pairsI; e2 = e2I; rows = rowsI; cur = curI; ecur = ecurI;
                   bb = b - NBu; Nrows = NRi; }
    int cnt = min(cur[bb], CAPB);
    if (t == 0) sbase = atomicAdd(ecur, cnt);
    if (t < RPB) hist[t] = 0;
    __syncthreads();
    const int2* pb = pairs + (size_t)bb * CAPB;
    for (int i = t; i < cnt; i += 1024)
        atomicAdd(&hist[pb[i].y & (RPB - 1)], 1);
    __syncthreads();
    // 256-bin exclusive scan: intra-wave shfl scan (waves 0-3) + wave-total combine
    int v = 0, incl = 0;
    if (t < RPB) {
        v = hist[t];
        incl = v;
#pragma unroll
        for (int off = 1; off < 64; off <<= 1) {
            int nn = __shfl_up(incl, off, 64);
            if ((t & 63) >= off) incl += nn;
        }
        if ((t & 63) == 63) wsums[t >> 6] = incl;
    }
    __syncthreads();
    if (t < RPB) {
        int wexcl = 0;
        int wv = t >> 6;
        for (int k = 0; k < wv; ++k) wexcl += wsums[k];
        pos[t] = incl - v + wexcl;   // exclusive scan
    }
    if (t == 0) pos[RPB] = cnt;
    __syncthreads();
    int base = sbase;
    int r0 = bb * RPB;
    if (t < RPB) {
        int row = r0 + t;
        if (row < Nrows) rows[row] = make_int2(base + pos[t], base + pos[t + 1]);
    }
    __syncthreads();   // rows reads of pos[] must complete before scatter mutates pos
    for (int i = t; i < cnt; i += 1024) {
        int2 pe = pb[i];             // L2-hot re-read
        int r = pe.y & (RPB - 1);
        int p = atomicAdd(&pos[r], 1);
        e2[base + p] = make_int2(pe.x, pe.y & ~(RPB - 1));
    }
}

// ---------------- compute ----------------

__device__ inline float group8_sum(float v) {
    v += __shfl_xor(v, 1, 64);
    v += __shfl_xor(v, 2, 64);
    v += __shfl_xor(v, 4, 64);
    return v;
}

// Gather-accumulate one CSR row from bf16 table.
// Wave layout: g = lane>>3 (8 edge slots), l = lane&7 (8 features each, 16B load).
// 16 edges / 2KB in flight per unrolled body.
__device__ inline void spmm_row_bf(const int2* __restrict__ e2, int j0, int j1,
                                   const u16* __restrict__ x, int g, int l,
                                   float a[8]) {
    float a0[8] = {0, 0, 0, 0, 0, 0, 0, 0};
    float a1[8] = {0, 0, 0, 0, 0, 0, 0, 0};
    int j = j0;
    for (; j + 16 <= j1; j += 16) {
        int2 ea = e2[j + g];
        int2 eb = e2[j + 8 + g];
        uint4 ua = *(const uint4*)(x + (size_t)ea.x * KDIM + l * 8);
        uint4 ub = *(const uint4*)(x + (size_t)eb.x * KDIM + l * 8);
        float wa = __int_as_float(ea.y), wb = __int_as_float(eb.y);
        float fa[8], fb[8];
        bf8_to_f32(ua, fa);
        bf8_to_f32(ub, fb);
#pragma unroll
        for (int c = 0; c < 8; ++c) {
            a0[c] += wa * fa[c];
            a1[c] += wb * fb[c];
        }
    }
    for (; j < j1; j += 8) {
        if (j + g < j1) {
            int2 ea = e2[j + g];
            uint4 ua = *(const uint4*)(x + (size_t)ea.x * KDIM + l * 8);
            float wa = __int_as_float(ea.y);
            float fa[8];
            bf8_to_f32(ua, fa);
#pragma unroll
            for (int c = 0; c < 8; ++c) a0[c] += wa * fa[c];
        }
    }
#pragma unroll
    for (int c = 0; c < 8; ++c) {
        float v = a0[c] + a1[c];
        v += __shfl_xor(v, 8, 64);
        v += __shfl_xor(v, 16, 64);
        v += __shfl_xor(v, 32, 64);
        a[c] = v;
    }
}

// one-shot f32 -> bf16 convert for Gu|Gi -> bufA and Gis -> gis0 (single launch)
__global__ void cvt_all(const float* __restrict__ Gu, const float* __restrict__ Gi,
                        const float* __restrict__ Gis, u16* __restrict__ bufA,
                        u16* __restrict__ gis0, int nu8, int na8, int ntot8) {
    int i = blockIdx.x * blockDim.x + threadIdx.x;
    if (i >= ntot8) return;
    const float* p;
    u16* o;
    if (i < nu8)      { p = Gu  + (size_t)i * 8;          o = bufA + (size_t)i * 8; }
    else if (i < na8) { p = Gi  + (size_t)(i - nu8) * 8;  o = bufA + (size_t)i * 8; }
    else              { p = Gis + (size_t)(i - na8) * 8;  o = gis0 + (size_t)(i - na8) * 8; }
    f4 v0 = ld4(p);
    f4 v1 = ld4(p + 4);
    uint4 pk;
    pk.x = pack_bf16(v0.x, v0.y);
    pk.y = pack_bf16(v0.z, v0.w);
    pk.z = pack_bf16(v1.x, v1.y);
    pk.w = pack_bf16(v1.z, v1.w);
    *(uint4*)o = pk;
}

// Fused layer 1: rows [0,nui) = UI layer1 (xu -> l2norm -> yu bf16);
// rows [nui,nui+nii) = II hop1 (xi -> yi bf16, no norm).
__global__ void spmm_fused_l1(const int2* __restrict__ ui_rows, const int2* __restrict__ ui_e,
                              const u16* __restrict__ xu, u16* __restrict__ yu,
                              const int2* __restrict__ ii_rows, const int2* __restrict__ ii_e,
                              const u16* __restrict__ xi, u16* __restrict__ yi,
                              int nui, int nii) {
    const int lane = threadIdx.x & 63;
    const int g = lane >> 3, l = lane & 7;
    const int r = (blockIdx.x * blockDim.x + threadIdx.x) >> 6;
    if (r < nui) {
        int2 se = ui_rows[r];
        float a[8];
        spmm_row_bf(ui_e, se.x, se.y, xu, g, l, a);
        float loc = 0.f;
#pragma unroll
        for (int c = 0; c < 8; ++c) loc += a[c] * a[c];
        float ss = group8_sum(loc);
        float inv = 1.f / fmaxf(sqrtf(ss), EPSF);
        if (g == 0) {
            uint4 pk;
            pk.x = pack_bf16(a[0] * inv, a[1] * inv);
            pk.y = pack_bf16(a[2] * inv, a[3] * inv);
            pk.z = pack_bf16(a[4] * inv, a[5] * inv);
            pk.w = pack_bf16(a[6] * inv, a[7] * inv);
            *(uint4*)(yu + (size_t)r * KDIM + l * 8) = pk;
        }
    } else if (r < nui + nii) {
        int rr = r - nui;
        int2 se = ii_rows[rr];
        float a[8];
        spmm_row_bf(ii_e, se.x, se.y, xi, g, l, a);
        if (g == 0) {
            uint4 pk;
            pk.x = pack_bf16(a[0], a[1]);
            pk.y = pack_bf16(a[2], a[3]);
            pk.z = pack_bf16(a[4], a[5]);
            pk.w = pack_bf16(a[6], a[7]);
            *(uint4*)(yi + (size_t)rr * KDIM + l * 8) = pk;
        }
    }
}

// Fused layer 2: UI layer2 (norm, bf16 out) + II hop2 (no norm, f32 out)
__global__ void spmm_fused_l2(const int2* __restrict__ ui_rows, const int2* __restrict__ ui_e,
                              const u16* __restrict__ xu, u16* __restrict__ yu,
                              const int2* __restrict__ ii_rows, const int2* __restrict__ ii_e,
                              const u16* __restrict__ xi, float* __restrict__ yi,
                              int nui, int nii) {
    const int lane = threadIdx.x & 63;
    const int g = lane >> 3, l = lane & 7;
    const int r = (blockIdx.x * blockDim.x + threadIdx.x) >> 6;
    if (r < nui) {
        int2 se = ui_rows[r];
        float a[8];
        spmm_row_bf(ui_e, se.x, se.y, xu, g, l, a);
        float loc = 0.f;
#pragma unroll
        for (int c = 0; c < 8; ++c) loc += a[c] * a[c];
        float ss = group8_sum(loc);
        float inv = 1.f / fmaxf(sqrtf(ss), EPSF);
        if (g == 0) {
            uint4 pk;
            pk.x = pack_bf16(a[0] * inv, a[1] * inv);
            pk.y = pack_bf16(a[2] * inv, a[3] * inv);
            pk.z = pack_bf16(a[4] * inv, a[5] * inv);
            pk.w = pack_bf16(a[6] * inv, a[7] * inv);
            *(uint4*)(yu + (size_t)r * KDIM + l * 8) = pk;
        }
    } else if (r < nui + nii) {
        int rr = r - nui;
        int2 se = ii_rows[rr];
        float a[8];
        spmm_row_bf(ii_e, se.x, se.y, xi, g, l, a);
        if (g == 0) {
            float* yp = yi + (size_t)rr * KDIM + l * 8;
            *(f4*)yp = f4{a[0], a[1], a[2], a[3]};
            *(f4*)(yp + 4) = f4{a[4], a[5], a[6], a[7]};
        }
    }
}

// Last UI layer fused with finalize:
// n3 = l2norm(spmm(n2));  out = (ego + n1 + n2 + n3)/4  (+ l2norm(gis) for items)
__global__ void spmm_pull_norm_final(const int2* __restrict__ rows, const int2* __restrict__ e2,
                                     const u16* __restrict__ x,   // n2 (also gather table)
                                     const u16* __restrict__ n1,
                                     const float* __restrict__ Gu,
                                     const float* __restrict__ Gi,
                                     const float* __restrict__ gis,
                                     float* __restrict__ out, int nrows) {
    const int lane = threadIdx.x & 63;
    const int g = lane >> 3, l = lane & 7;
    const int r = (blockIdx.x * blockDim.x + threadIdx.x) >> 6;
    if (r >= nrows) return;
    int2 se = rows[r];
    float a[8];
    spmm_row_bf(e2, se.x, se.y, x, g, l, a);
    float loc = 0.f;
#pragma unroll
    for (int c = 0; c < 8; ++c) loc += a[c] * a[c];
    float ss = group8_sum(loc);
    float inv = 1.f / fmaxf(sqrtf(ss), EPSF);
    if (g != 0) return;
    // ego from inputs (pure stream, never reused -> non-temporal)
    const float* ep = (r < U_N) ? Gu + (size_t)r * KDIM + l * 8
                                : Gi + (size_t)(r - U_N) * KDIM + l * 8;
    f4 e0 = __builtin_nontemporal_load((const f4*)ep);
    f4 e1 = __builtin_nontemporal_load((const f4*)(ep + 4));
    // n1, n2 rows (bf16, L3-hot: n2 is the gather table of this very kernel)
    uint4 u1 = *(const uint4*)(n1 + (size_t)r * KDIM + l * 8);
    uint4 u2 = *(const uint4*)(x + (size_t)r * KDIM + l * 8);
    float f1[8], f2[8];
    bf8_to_f32(u1, f1);
    bf8_to_f32(u2, f2);
    f4 v0 = (e0 + f4{f1[0], f1[1], f1[2], f1[3]} + f4{f2[0], f2[1], f2[2], f2[3]}
                + f4{a[0] * inv, a[1] * inv, a[2] * inv, a[3] * inv}) * 0.25f;
    f4 v1 = (e1 + f4{f1[4], f1[5], f1[6], f1[7]} + f4{f2[4], f2[5], f2[6], f2[7]}
                + f4{a[4] * inv, a[5] * inv, a[6] * inv, a[7] * inv}) * 0.25f;
    if (r >= U_N) {
        const float* gp = gis + (size_t)(r - U_N) * KDIM + l * 8;
        f4 g0 = ld4(gp);
        f4 g1 = ld4(gp + 4);
        float loc2 = g0.x * g0.x + g0.y * g0.y + g0.z * g0.z + g0.w * g0.w
                   + g1.x * g1.x + g1.y * g1.y + g1.z * g1.z + g1.w * g1.w;
        // only lanes 0..7 here; group8_sum works within this group
        float ss2 = group8_sum(loc2);
        float inv2 = 1.f / fmaxf(sqrtf(ss2), EPSF);
        v0 += g0 * inv2;
        v1 += g1 * inv2;
    }
    float* op = out + (size_t)r * KDIM + l * 8;
    __builtin_nontemporal_store(v0, (f4*)op);
    __builtin_nontemporal_store(v1, (f4*)(op + 4));
}

extern "C" void kernel_launch(void* const* d_in, const int* in_sizes, int n_in,
                              void* d_out, int out_size, void* d_ws, size_t ws_size,
                              hipStream_t stream) {
    const float* Gu     = (const float*)d_in[0];
    const float* Gi     = (const float*)d_in[1];
    const float* Gis    = (const float*)d_in[2];
    const float* ii_w   = (const float*)d_in[3];
    const float* ui_w   = (const float*)d_in[4];
    const int*   ii_src = (const int*)d_in[5];
    const int*   ii_dst = (const int*)d_in[6];
    const int*   ui_src = (const int*)d_in[7];
    const int*   ui_dst = (const int*)d_in[8];
    const int E_II = in_sizes[5];
    const int E_UI = in_sizes[7];

    const int NR    = U_N + I_N;                     // 150000 rows
    const size_t NI = (size_t)I_N * KDIM;            // 3.2M elems
    const size_t NA = (size_t)NR * KDIM;             // 9.6M elems

    const int NB_UI = (NR + RPB - 1) / RPB;    // 586
    const int NB_II = (I_N + RPB - 1) / RPB;   // 196

    // ---- workspace layout (all segments 16B-aligned by construction) ----
    // The first 64MB region (bufA..gisB) is aliased by the pairs scratch
    // during the CSR build (57.7MB needed); it is dead until cvt_all.
    u16*  bufA = (u16*)d_ws;               // NA bf16 (19.2MB)
    u16*  bufB = bufA + NA;                // NA bf16
    u16*  gis0 = bufB + NA;                // NI bf16 (cvt of Gis)
    u16*  gisA = gis0 + NI;                // NI bf16
    float* gisB = (float*)(gisA + NI);     // NI f32
    int2*  ui_e = (int2*)(gisB + NI);      // E_UI (compact)
    int2*  ii_e = ui_e + E_UI;             // E_II (compact)
    int2*  ui_rows = ii_e + E_II;          // NR
    int2*  ii_rows = ui_rows + NR;         // I_N
    int*   curU = (int*)(ii_rows + I_N);   // NB_UI
    int*   curI = curU + NB_UI;            // NB_II
    int*   ecur = curI + NB_II;            // 2 (UI, II e2 tickets)

    // pairs scratch (bucket-strided, CAPB each): (586+196)*9216*8B = 57.7MB
    int2* pairsU = (int2*)bufA;
    int2* pairsI = pairsU + (size_t)NB_UI * CAPB;

    float* out = (float*)d_out;

    const int nchU = (E_UI + CH - 1) / CH;     // 293
    const int nchI = (E_II + CH - 1) / CH;     // 98

    // ---- build both CSRs: memset cursors -> partition -> per-bucket sort ----
    (void)hipMemsetAsync(curU, 0, (NB_UI + NB_II + 2) * sizeof(int), stream);
    bpart2_k<<<nchU + nchI, 1024, 0, stream>>>(
        ui_src, ui_dst, ui_w, curU, pairsU, nchU, E_UI,
        ii_src, ii_dst, ii_w, curI, pairsI, E_II);
    bfill2_k<<<NB_UI + NB_II, 1024, 0, stream>>>(
        curU, pairsU, ui_e, ui_rows, NB_UI, NR, ecur,
        curI, pairsI, ii_e, ii_rows, I_N, ecur + 1);

    // ---- all f32->bf16 converts in one launch (after builds free the scratch) ----
    const int nu8 = (int)((size_t)U_N * KDIM / 8);
    const int na8 = (int)(NA / 8);
    const int nt8 = (int)((NA + NI) / 8);
    cvt_all<<<(nt8 + 255) / 256, 256, 0, stream>>>(Gu, Gi, Gis, bufA, gis0, nu8, na8, nt8);

    // ---- fused layers: UI layer k overlapped with II hop k; final fuses mean ----
    const int NTOT = NR + I_N;   // 200000 rows per fused launch
    spmm_fused_l1<<<(NTOT + 3) / 4, 256, 0, stream>>>(ui_rows, ui_e, bufA, bufB,
                                                      ii_rows, ii_e, gis0, gisA, NR, I_N);
    spmm_fused_l2<<<(NTOT + 3) / 4, 256, 0, stream>>>(ui_rows, ui_e, bufB, bufA,
                                                      ii_rows, ii_e, gisA, gisB, NR, I_N);
    spmm_pull_norm_final<<<(NR + 3) / 4, 256, 0, stream>>>(ui_rows, ui_e, bufA, bufB,
                                                           Gu, Gi, gisB, out, NR);
}

// Round 11
// 623.230 us; speedup vs baseline: 1.0355x; 1.0355x over previous
//
#include <hip/hip_runtime.h>
#include <hip/hip_bf16.h>

constexpr int U_N = 100000;
constexpr int I_N = 50000;
constexpr int KDIM = 64;
constexpr float EPSF = 1e-12f;

// bucketed CSR build params
constexpr int RPB = 256;        // rows per bucket (dst & 255 fits in low 8 w-mantissa bits)
constexpr int BSHIFT = 8;       // bucket = dst >> 8
constexpr int CH = 16384;       // edges per partition chunk (LDS-sorted whole chunk, 128KB)
constexpr int CAPB = 9216;      // bfill LDS concat capacity (mean bucket 8192, +11 sigma)

typedef float f4 __attribute__((ext_vector_type(4)));
typedef unsigned short u16;

__device__ inline f4 ld4(const float* p) { return *(const f4*)p; }

// pack two f32 -> two bf16 (RNE) in one uint32
__device__ inline unsigned pack_bf16(float a, float b) {
    unsigned ua = __float_as_uint(a);
    unsigned ub = __float_as_uint(b);
    ua += 0x7fffu + ((ua >> 16) & 1u);
    ub += 0x7fffu + ((ub >> 16) & 1u);
    return (ua >> 16) | (ub & 0xffff0000u);
}

// unpack 8 bf16 (uint4) -> 8 f32
__device__ inline void bf8_to_f32(uint4 u, float* f) {
    unsigned w0 = u.x, w1 = u.y, w2 = u.z, w3 = u.w;
    f[0] = __uint_as_float(w0 << 16);  f[1] = __uint_as_float(w0 & 0xffff0000u);
    f[2] = __uint_as_float(w1 << 16);  f[3] = __uint_as_float(w1 & 0xffff0000u);
    f[4] = __uint_as_float(w2 << 16);  f[5] = __uint_as_float(w2 & 0xffff0000u);
    f[6] = __uint_as_float(w3 << 16);  f[7] = __uint_as_float(w3 & 0xffff0000u);
}

// exclusive prefix over 1024 threads; wsum = shared int[16]; has one internal barrier.
// Caller must barrier before reusing wsum.
__device__ inline int block_exscan(int v, int t, int* wsum) {
    int incl = v;
#pragma unroll
    for (int off = 1; off < 64; off <<= 1) {
        int nn = __shfl_up(incl, off, 64);
        if ((t & 63) >= off) incl += nn;
    }
    if ((t & 63) == 63) wsum[t >> 6] = incl;
    __syncthreads();
    int wex = 0;
    int wv = t >> 6;
    for (int k = 0; k < wv; ++k) wex += wsum[k];
    return incl - v + wex;
}

// ---------------- bucketed CSR build: all global writes linear ----------------
// Pass 1 (bpart2): one chunk per block. Histogram dst buckets in LDS, wave-scan,
// sort the chunk by bucket INSIDE LDS, then write the sorted chunk to its own
// contiguous chunk region (coalesced, single-writer lines, write-once) plus
// per-(chunk,bucket) count+offset meta. No global atomics, no scattered writes.
// dlo (dst&255) is embedded in the low 8 mantissa bits of w -> no dlo array.
__global__ __launch_bounds__(1024) void bpart2_k(
        const int* __restrict__ srcU, const int* __restrict__ dstU,
        const float* __restrict__ wU, int2* __restrict__ chunkU,
        int* __restrict__ cntUm, int* __restrict__ offUm, int nchU, int EU, int NBu,
        const int* __restrict__ srcI, const int* __restrict__ dstI,
        const float* __restrict__ wI, int2* __restrict__ chunkI,
        int* __restrict__ cntIm, int* __restrict__ offIm, int EI, int NBi) {
    __shared__ int2 st[CH];       // 128KB: chunk sorted by bucket
    __shared__ int hist[1024];
    __shared__ int sA[1024];
    __shared__ int wsum[16];
    int t = threadIdx.x;
    int c = blockIdx.x;
    const int* src; const int* dst; const float* w; int2* chunk;
    int* cntm; int* offm; int cb, E, NB, cidx;
    if (c < nchU) { src = srcU; dst = dstU; w = wU; chunk = chunkU;
                    cntm = cntUm; offm = offUm; cidx = c; cb = c * CH; E = EU; NB = NBu; }
    else          { src = srcI; dst = dstI; w = wI; chunk = chunkI;
                    cntm = cntIm; offm = offIm; cidx = c - nchU; cb = cidx * CH; E = EI; NB = NBi; }
    int n = min(CH, E - cb);
    hist[t] = 0;
    __syncthreads();
    for (int j = t; j < n; j += 1024)
        atomicAdd(&hist[dst[cb + j] >> BSHIFT], 1);
    __syncthreads();
    int v = hist[t];
    int ex = block_exscan(v, t, wsum);
    sA[t] = ex;
    if (t < NB) {
        cntm[(size_t)cidx * NB + t] = v;
        offm[(size_t)cidx * NB + t] = ex;
    }
    hist[t] = 0;   // becomes local placement cursor
    __syncthreads();
    for (int j = t; j < n; j += 1024) {
        int i = cb + j;
        int d = dst[i];             // L2-hot re-read
        int b = d >> BSHIFT;
        int ew = (int)((__float_as_uint(w[i]) & 0xFFFFFF00u) | (unsigned)(d & (RPB - 1)));
        int local = atomicAdd(&hist[b], 1);
        st[sA[b] + local] = make_int2(src[i], ew);
    }
    __syncthreads();
    for (int j = t; j < n; j += 1024)
        chunk[(size_t)cb + j] = st[j];   // linear, coalesced, write-once
}

// Pass 2 (bfill2): one bucket per block. Scan per-chunk counts (shfl), gather the
// bucket's runs from every chunk region into LDS, row-histogram + scan, emit int2
// row ranges, counting-sort scatter into compact e2 claimed via atomic ticket
// (bucket placement order is schedule-dependent; row ranges carry absolute
// positions so compute is exact).
__global__ __launch_bounds__(1024) void bfill2_k(
        const int2* __restrict__ chunkU, const int* __restrict__ cntUm,
        const int* __restrict__ offUm, int nchU,
        int2* __restrict__ e2U, int2* __restrict__ rowsU, int NBu, int NRu,
        int* __restrict__ ecurU,
        const int2* __restrict__ chunkI, const int* __restrict__ cntIm,
        const int* __restrict__ offIm, int nchI,
        int2* __restrict__ e2I, int2* __restrict__ rowsI, int NBi, int NRi,
        int* __restrict__ ecurI) {
    __shared__ int2 st[CAPB];     // 72KB: bucket concat
    __shared__ int hist[RPB];
    __shared__ int pos[RPB + 1];
    __shared__ int wsum[16];
    __shared__ int sbase, stot;
    int t = threadIdx.x;  // 1024
    int b = blockIdx.x;
    const int2* chunk; const int* cntm; const int* offm; int2* e2; int2* rows;
    int* ecur; int bb, Nrows, NB, nch;
    if (b < NBu) { chunk = chunkU; cntm = cntUm; offm = offUm; nch = nchU;
                   e2 = e2U; rows = rowsU; ecur = ecurU; bb = b; Nrows = NRu; NB = NBu; }
    else         { chunk = chunkI; cntm = cntIm; offm = offIm; nch = nchI;
                   e2 = e2I; rows = rowsI; ecur = ecurI; bb = b - NBu; Nrows = NRi; NB = NBi; }
    int myc = 0, myloc = 0;
    if (t < nch) {
        myc   = cntm[(size_t)t * NB + bb];
        myloc = offm[(size_t)t * NB + bb];
    }
    int mystart = block_exscan(myc, t, wsum);
    if (t == 1023) stot = mystart;   // t=1023 >= nch -> myc=0 -> mystart == total
    __syncthreads();
    int cnt = min(stot, CAPB);
    if (t == 0) sbase = atomicAdd(ecur, cnt);
    if (t < RPB) hist[t] = 0;
    // gather this bucket's run from each chunk into LDS
    if (t < nch && myc > 0) {
        const int2* sp = chunk + (size_t)t * CH + myloc;
        for (int k = 0; k < myc; ++k) {
            int p = mystart + k;
            if (p < CAPB) st[p] = sp[k];
        }
    }
    __syncthreads();
    for (int i = t; i < cnt; i += 1024)
        atomicAdd(&hist[st[i].y & (RPB - 1)], 1);
    __syncthreads();
    int hv = (t < RPB) ? hist[t] : 0;
    int hex = block_exscan(hv, t, wsum);
    if (t < RPB) pos[t] = hex;
    if (t == 0) pos[RPB] = cnt;
    __syncthreads();
    int base = sbase;
    int r0 = bb * RPB;
    if (t < RPB) {
        int row = r0 + t;
        if (row < Nrows) rows[row] = make_int2(base + pos[t], base + pos[t + 1]);
    }
    __syncthreads();   // rows reads of pos[] must complete before scatter mutates pos
    for (int i = t; i < cnt; i += 1024) {
        int2 pe = st[i];
        int r = pe.y & (RPB - 1);
        int p = atomicAdd(&pos[r], 1);
        e2[base + p] = make_int2(pe.x, pe.y & ~(RPB - 1));
    }
}

// ---------------- compute ----------------

__device__ inline float group8_sum(float v) {
    v += __shfl_xor(v, 1, 64);
    v += __shfl_xor(v, 2, 64);
    v += __shfl_xor(v, 4, 64);
    return v;
}

// Gather-accumulate one CSR row from bf16 table.
// Wave layout: g = lane>>3 (8 edge slots), l = lane&7 (8 features each, 16B load).
// 16 edges / 2KB in flight per unrolled body.
__device__ inline void spmm_row_bf(const int2* __restrict__ e2, int j0, int j1,
                                   const u16* __restrict__ x, int g, int l,
                                   float a[8]) {
    float a0[8] = {0, 0, 0, 0, 0, 0, 0, 0};
    float a1[8] = {0, 0, 0, 0, 0, 0, 0, 0};
    int j = j0;
    for (; j + 16 <= j1; j += 16) {
        int2 ea = e2[j + g];
        int2 eb = e2[j + 8 + g];
        uint4 ua = *(const uint4*)(x + (size_t)ea.x * KDIM + l * 8);
        uint4 ub = *(const uint4*)(x + (size_t)eb.x * KDIM + l * 8);
        float wa = __int_as_float(ea.y), wb = __int_as_float(eb.y);
        float fa[8], fb[8];
        bf8_to_f32(ua, fa);
        bf8_to_f32(ub, fb);
#pragma unroll
        for (int c = 0; c < 8; ++c) {
            a0[c] += wa * fa[c];
            a1[c] += wb * fb[c];
        }
    }
    for (; j < j1; j += 8) {
        if (j + g < j1) {
            int2 ea = e2[j + g];
            uint4 ua = *(const uint4*)(x + (size_t)ea.x * KDIM + l * 8);
            float wa = __int_as_float(ea.y);
            float fa[8];
            bf8_to_f32(ua, fa);
#pragma unroll
            for (int c = 0; c < 8; ++c) a0[c] += wa * fa[c];
        }
    }
#pragma unroll
    for (int c = 0; c < 8; ++c) {
        float v = a0[c] + a1[c];
        v += __shfl_xor(v, 8, 64);
        v += __shfl_xor(v, 16, 64);
        v += __shfl_xor(v, 32, 64);
        a[c] = v;
    }
}

// one-shot f32 -> bf16 convert for Gu|Gi -> bufA and Gis -> gis0 (single launch)
__global__ void cvt_all(const float* __restrict__ Gu, const float* __restrict__ Gi,
                        const float* __restrict__ Gis, u16* __restrict__ bufA,
                        u16* __restrict__ gis0, int nu8, int na8, int ntot8) {
    int i = blockIdx.x * blockDim.x + threadIdx.x;
    if (i >= ntot8) return;
    const float* p;
    u16* o;
    if (i < nu8)      { p = Gu  + (size_t)i * 8;          o = bufA + (size_t)i * 8; }
    else if (i < na8) { p = Gi  + (size_t)(i - nu8) * 8;  o = bufA + (size_t)i * 8; }
    else              { p = Gis + (size_t)(i - na8) * 8;  o = gis0 + (size_t)(i - na8) * 8; }
    f4 v0 = ld4(p);
    f4 v1 = ld4(p + 4);
    uint4 pk;
    pk.x = pack_bf16(v0.x, v0.y);
    pk.y = pack_bf16(v0.z, v0.w);
    pk.z = pack_bf16(v1.x, v1.y);
    pk.w = pack_bf16(v1.z, v1.w);
    *(uint4*)o = pk;
}

// Fused layer 1: rows [0,nui) = UI layer1 (xu -> l2norm -> yu bf16);
// rows [nui,nui+nii) = II hop1 (xi -> yi bf16, no norm).
__global__ void spmm_fused_l1(const int2* __restrict__ ui_rows, const int2* __restrict__ ui_e,
                              const u16* __restrict__ xu, u16* __restrict__ yu,
                              const int2* __restrict__ ii_rows, const int2* __restrict__ ii_e,
                              const u16* __restrict__ xi, u16* __restrict__ yi,
                              int nui, int nii) {
    const int lane = threadIdx.x & 63;
    const int g = lane >> 3, l = lane & 7;
    const int r = (blockIdx.x * blockDim.x + threadIdx.x) >> 6;
    if (r < nui) {
        int2 se = ui_rows[r];
        float a[8];
        spmm_row_bf(ui_e, se.x, se.y, xu, g, l, a);
        float loc = 0.f;
#pragma unroll
        for (int c = 0; c < 8; ++c) loc += a[c] * a[c];
        float ss = group8_sum(loc);
        float inv = 1.f / fmaxf(sqrtf(ss), EPSF);
        if (g == 0) {
            uint4 pk;
            pk.x = pack_bf16(a[0] * inv, a[1] * inv);
            pk.y = pack_bf16(a[2] * inv, a[3] * inv);
            pk.z = pack_bf16(a[4] * inv, a[5] * inv);
            pk.w = pack_bf16(a[6] * inv, a[7] * inv);
            *(uint4*)(yu + (size_t)r * KDIM + l * 8) = pk;
        }
    } else if (r < nui + nii) {
        int rr = r - nui;
        int2 se = ii_rows[rr];
        float a[8];
        spmm_row_bf(ii_e, se.x, se.y, xi, g, l, a);
        if (g == 0) {
            uint4 pk;
            pk.x = pack_bf16(a[0], a[1]);
            pk.y = pack_bf16(a[2], a[3]);
            pk.z = pack_bf16(a[4], a[5]);
            pk.w = pack_bf16(a[6], a[7]);
            *(uint4*)(yi + (size_t)rr * KDIM + l * 8) = pk;
        }
    }
}

// Fused layer 2: UI layer2 (norm, bf16 out) + II hop2 (no norm, f32 out)
__global__ void spmm_fused_l2(const int2* __restrict__ ui_rows, const int2* __restrict__ ui_e,
                              const u16* __restrict__ xu, u16* __restrict__ yu,
                              const int2* __restrict__ ii_rows, const int2* __restrict__ ii_e,
                              const u16* __restrict__ xi, float* __restrict__ yi,
                              int nui, int nii) {
    const int lane = threadIdx.x & 63;
    const int g = lane >> 3, l = lane & 7;
    const int r = (blockIdx.x * blockDim.x + threadIdx.x) >> 6;
    if (r < nui) {
        int2 se = ui_rows[r];
        float a[8];
        spmm_row_bf(ui_e, se.x, se.y, xu, g, l, a);
        float loc = 0.f;
#pragma unroll
        for (int c = 0; c < 8; ++c) loc += a[c] * a[c];
        float ss = group8_sum(loc);
        float inv = 1.f / fmaxf(sqrtf(ss), EPSF);
        if (g == 0) {
            uint4 pk;
            pk.x = pack_bf16(a[0] * inv, a[1] * inv);
            pk.y = pack_bf16(a[2] * inv, a[3] * inv);
            pk.z = pack_bf16(a[4] * inv, a[5] * inv);
            pk.w = pack_bf16(a[6] * inv, a[7] * inv);
            *(uint4*)(yu + (size_t)r * KDIM + l * 8) = pk;
        }
    } else if (r < nui + nii) {
        int rr = r - nui;
        int2 se = ii_rows[rr];
        float a[8];
        spmm_row_bf(ii_e, se.x, se.y, xi, g, l, a);
        if (g == 0) {
            float* yp = yi + (size_t)rr * KDIM + l * 8;
            *(f4*)yp = f4{a[0], a[1], a[2], a[3]};
            *(f4*)(yp + 4) = f4{a[4], a[5], a[6], a[7]};
        }
    }
}

// Last UI layer fused with finalize:
// n3 = l2norm(spmm(n2));  out = (ego + n1 + n2 + n3)/4  (+ l2norm(gis) for items)
__global__ void spmm_pull_norm_final(const int2* __restrict__ rows, const int2* __restrict__ e2,
                                     const u16* __restrict__ x,   // n2 (also gather table)
                                     const u16* __restrict__ n1,
                                     const float* __restrict__ Gu,
                                     const float* __restrict__ Gi,
                                     const float* __restrict__ gis,
                                     float* __restrict__ out, int nrows) {
    const int lane = threadIdx.x & 63;
    const int g = lane >> 3, l = lane & 7;
    const int r = (blockIdx.x * blockDim.x + threadIdx.x) >> 6;
    if (r >= nrows) return;
    int2 se = rows[r];
    float a[8];
    spmm_row_bf(e2, se.x, se.y, x, g, l, a);
    float loc = 0.f;
#pragma unroll
    for (int c = 0; c < 8; ++c) loc += a[c] * a[c];
    float ss = group8_sum(loc);
    float inv = 1.f / fmaxf(sqrtf(ss), EPSF);
    if (g != 0) return;
    // ego from inputs (pure stream, never reused -> non-temporal)
    const float* ep = (r < U_N) ? Gu + (size_t)r * KDIM + l * 8
                                : Gi + (size_t)(r - U_N) * KDIM + l * 8;
    f4 e0 = __builtin_nontemporal_load((const f4*)ep);
    f4 e1 = __builtin_nontemporal_load((const f4*)(ep + 4));
    // n1, n2 rows (bf16, L3-hot: n2 is the gather table of this very kernel)
    uint4 u1 = *(const uint4*)(n1 + (size_t)r * KDIM + l * 8);
    uint4 u2 = *(const uint4*)(x + (size_t)r * KDIM + l * 8);
    float f1[8], f2[8];
    bf8_to_f32(u1, f1);
    bf8_to_f32(u2, f2);
    f4 v0 = (e0 + f4{f1[0], f1[1], f1[2], f1[3]} + f4{f2[0], f2[1], f2[2], f2[3]}
                + f4{a[0] * inv, a[1] * inv, a[2] * inv, a[3] * inv}) * 0.25f;
    f4 v1 = (e1 + f4{f1[4], f1[5], f1[6], f1[7]} + f4{f2[4], f2[5], f2[6], f2[7]}
                + f4{a[4] * inv, a[5] * inv, a[6] * inv, a[7] * inv}) * 0.25f;
    if (r >= U_N) {
        const float* gp = gis + (size_t)(r - U_N) * KDIM + l * 8;
        f4 g0 = ld4(gp);
        f4 g1 = ld4(gp + 4);
        float loc2 = g0.x * g0.x + g0.y * g0.y + g0.z * g0.z + g0.w * g0.w
                   + g1.x * g1.x + g1.y * g1.y + g1.z * g1.z + g1.w * g1.w;
        // only lanes 0..7 here; group8_sum works within this group
        float ss2 = group8_sum(loc2);
        float inv2 = 1.f / fmaxf(sqrtf(ss2), EPSF);
        v0 += g0 * inv2;
        v1 += g1 * inv2;
    }
    float* op = out + (size_t)r * KDIM + l * 8;
    __builtin_nontemporal_store(v0, (f4*)op);
    __builtin_nontemporal_store(v1, (f4*)(op + 4));
}

extern "C" void kernel_launch(void* const* d_in, const int* in_sizes, int n_in,
                              void* d_out, int out_size, void* d_ws, size_t ws_size,
                              hipStream_t stream) {
    const float* Gu     = (const float*)d_in[0];
    const float* Gi     = (const float*)d_in[1];
    const float* Gis    = (const float*)d_in[2];
    const float* ii_w   = (const float*)d_in[3];
    const float* ui_w   = (const float*)d_in[4];
    const int*   ii_src = (const int*)d_in[5];
    const int*   ii_dst = (const int*)d_in[6];
    const int*   ui_src = (const int*)d_in[7];
    const int*   ui_dst = (const int*)d_in[8];
    const int E_II = in_sizes[5];
    const int E_UI = in_sizes[7];

    const int NR    = U_N + I_N;                     // 150000 rows
    const size_t NI = (size_t)I_N * KDIM;            // 3.2M elems
    const size_t NA = (size_t)NR * KDIM;             // 9.6M elems

    const int NB_UI = (NR + RPB - 1) / RPB;    // 586
    const int NB_II = (I_N + RPB - 1) / RPB;   // 196
    const int nchU = (E_UI + CH - 1) / CH;     // 293
    const int nchI = (E_II + CH - 1) / CH;     // 98

    // ---- workspace layout (all segments 16B-aligned by construction) ----
    // The first 64MB region (bufA..gisB) is aliased by the chunk scratch
    // during the CSR build (51.3MB needed); it is dead until cvt_all.
    u16*  bufA = (u16*)d_ws;               // NA bf16 (19.2MB)
    u16*  bufB = bufA + NA;                // NA bf16
    u16*  gis0 = bufB + NA;                // NI bf16 (cvt of Gis)
    u16*  gisA = gis0 + NI;                // NI bf16
    float* gisB = (float*)(gisA + NI);     // NI f32
    int2*  ui_e = (int2*)(gisB + NI);      // E_UI (compact)
    int2*  ii_e = ui_e + E_UI;             // E_II (compact)
    int2*  ui_rows = ii_e + E_II;          // NR
    int2*  ii_rows = ui_rows + NR;         // I_N
    int*   ecur  = (int*)(ii_rows + I_N);  // 2 (UI, II e2 tickets)
    int*   cntUm = ecur + 2;               // nchU*NB_UI
    int*   offUm = cntUm + (size_t)nchU * NB_UI;
    int*   cntIm = offUm + (size_t)nchU * NB_UI;   // nchI*NB_II
    int*   offIm = cntIm + (size_t)nchI * NB_II;

    // chunk scratch (chunk-contiguous, CH each): (293+98)*16384*8B = 51.3MB
    int2* chunkU = (int2*)bufA;
    int2* chunkI = chunkU + (size_t)nchU * CH;

    float* out = (float*)d_out;

    // ---- build both CSRs: memset tickets -> LDS-sort chunks -> per-bucket merge ----
    (void)hipMemsetAsync(ecur, 0, 2 * sizeof(int), stream);
    bpart2_k<<<nchU + nchI, 1024, 0, stream>>>(
        ui_src, ui_dst, ui_w, chunkU, cntUm, offUm, nchU, E_UI, NB_UI,
        ii_src, ii_dst, ii_w, chunkI, cntIm, offIm, E_II, NB_II);
    bfill2_k<<<NB_UI + NB_II, 1024, 0, stream>>>(
        chunkU, cntUm, offUm, nchU, ui_e, ui_rows, NB_UI, NR, ecur,
        chunkI, cntIm, offIm, nchI, ii_e, ii_rows, NB_II, I_N, ecur + 1);

    // ---- all f32->bf16 converts in one launch (after builds free the scratch) ----
    const int nu8 = (int)((size_t)U_N * KDIM / 8);
    const int na8 = (int)(NA / 8);
    const int nt8 = (int)((NA + NI) / 8);
    cvt_all<<<(nt8 + 255) / 256, 256, 0, stream>>>(Gu, Gi, Gis, bufA, gis0, nu8, na8, nt8);

    // ---- fused layers: UI layer k overlapped with II hop k; final fuses mean ----
    const int NTOT = NR + I_N;   // 200000 rows per fused launch
    spmm_fused_l1<<<(NTOT + 3) / 4, 256, 0, stream>>>(ui_rows, ui_e, bufA, bufB,
                                                      ii_rows, ii_e, gis0, gisA, NR, I_N);
    spmm_fused_l2<<<(NTOT + 3) / 4, 256, 0, stream>>>(ui_rows, ui_e, bufB, bufA,
                                                      ii_rows, ii_e, gisA, gisB, NR, I_N);
    spmm_pull_norm_final<<<(NR + 3) / 4, 256, 0, stream>>>(ui_rows, ui_e, bufA, bufB,
                                                           Gu, Gi, gisB, out, NR);
}